// Round 5
// baseline (186.821 us; speedup 1.0000x reference)
//
#include <hip/hip_runtime.h>
#include <hip/hip_bf16.h>
#include <stdint.h>

// ---- constants ----
// B=8, Cin=128, H=W=160, Ce=64, NH=4, HC=16, N=80, Cg=512, Co=128
// Single fused kernel: per 4h x 32w output tile,
//   pass A: embed 1x1 (MFMA, x gathered from global) -> E (LDS) -> scores
//           (MFMA vs Gpad) -> max/sigmoid -> aw (LDS)
//   pass B: 3x3 conv (MFMA, x staged to LDS per 32-cin chunk, dbuf) ->
//           BN -> gate by aw -> store

typedef __attribute__((ext_vector_type(8))) short short8;
typedef __attribute__((ext_vector_type(4))) float f32x4;

__device__ __forceinline__ unsigned short f2bf(float f) {
  unsigned int u = __float_as_uint(f);
  u += 0x7fff + ((u >> 16) & 1);   // round-to-nearest-even
  return (unsigned short)(u >> 16);
}

// ------------------------------------------------------------------
// P1: weight conversions + BN2 folding
//   W1t [64 ce][128 ci] bf16
//   Wpt [4 cs][9 tap][128 co][32 ci] bf16   (slab t = cs*9+tap at t*4096)
//   s2,t2 [128] f32
// ------------------------------------------------------------------
__global__ __launch_bounds__(256) void k_prep_misc(
    const float* __restrict__ w_embed, const float* __restrict__ w_proj,
    const float* __restrict__ g2, const float* __restrict__ b2,
    const float* __restrict__ rm2, const float* __restrict__ rv2,
    unsigned short* __restrict__ W1t, unsigned short* __restrict__ Wpt,
    float* __restrict__ s2, float* __restrict__ t2) {
  int idx = blockIdx.x * 256 + threadIdx.x;
  if (idx < 8192) { W1t[idx] = f2bf(w_embed[idx]); return; }
  idx -= 8192;
  if (idx < 147456) {
    int cs = idx / 36864, r = idx - cs * 36864;
    int tap = r >> 12, r2 = r & 4095;
    int co = r2 >> 5, ci5 = r2 & 31;
    int ci = cs * 32 + ci5;
    Wpt[idx] = f2bf(w_proj[(co * 128 + ci) * 9 + tap]);
    return;
  }
  idx -= 147456;
  if (idx < 128) {
    float s = g2[idx] * rsqrtf(rv2[idx] + 1e-3f);
    s2[idx] = s;
    t2[idx] = b2[idx] - rm2[idx] * s;
  }
}

// ------------------------------------------------------------------
// P2k: guide GEMM + BN1 folding
//   Gpad [8][4][80][32] bf16  (k<16: g_raw*s1 ; k>=16: 0)
//   Cst  [8][4][80] f32       (dot(g_raw, t1) per head)
// ------------------------------------------------------------------
__global__ __launch_bounds__(64) void k_guide(
    const float* __restrict__ guide, const float* __restrict__ Wg,
    const float* __restrict__ bg, const float* __restrict__ g1,
    const float* __restrict__ b1, const float* __restrict__ rm1,
    const float* __restrict__ rv1, unsigned short* __restrict__ Gpad,
    float* __restrict__ Cst) {
  int b = blockIdx.x / 80, n = blockIdx.x % 80;
  __shared__ float gs[512];
  const float* gr = guide + ((size_t)b * 80 + n) * 512;
  for (int i = threadIdx.x; i < 512; i += 64) gs[i] = gr[i];
  __syncthreads();
  int ce = threadIdx.x;
  const float* wr = Wg + (size_t)ce * 512;
  float acc = 0.f;
  for (int k = 0; k < 512; k += 4)
    acc += gs[k] * wr[k] + gs[k + 1] * wr[k + 1] + gs[k + 2] * wr[k + 2] +
           gs[k + 3] * wr[k + 3];
  float raw = acc + bg[ce];
  float s1 = g1[ce] * rsqrtf(rv1[ce] + 1e-3f);
  float t1 = b1[ce] - rm1[ce] * s1;
  int head = ce >> 4, c = ce & 15;
  size_t gp = (((size_t)b * 4 + head) * 80 + n) * 32;
  Gpad[gp + c] = f2bf(raw * s1);
  Gpad[gp + 16 + c] = 0;
  float cp = raw * t1;
  cp += __shfl_xor(cp, 1);
  cp += __shfl_xor(cp, 2);
  cp += __shfl_xor(cp, 4);
  cp += __shfl_xor(cp, 8);
  if (c == 0) Cst[((size_t)b * 4 + head) * 80 + n] = cp;
}

// ------------------------------------------------------------------
// K: fused mega kernel. Block tile [4h x 32w] x [128 co]; 4 waves =
// 2M(px) x 2N(co); per wave 64 px x 64 co. XCD-chunked: b = blk&7.
// LDS: XA 2 x [6 rows][34 px][4 slots][16B] = 2x13,056 B (conv staging,
//      overlaid by E [128 px][8 slots][16B] = 16 KB between passes)
//      + AWL [4 wv][2 heads][64 px] f32 = 2 KB.   Total 28,160 B.
// All LDS accesses slot-XOR swizzled to <=2-way (free) conflicts.
// ------------------------------------------------------------------
__global__ __launch_bounds__(256, 3) void k_mega(
    const float* __restrict__ x, const unsigned short* __restrict__ W1t,
    const unsigned short* __restrict__ Wpt, const unsigned short* __restrict__ Gpad,
    const float* __restrict__ Cst, const float* __restrict__ attn_bias,
    const float* __restrict__ s2, const float* __restrict__ t2,
    float* __restrict__ out) {
  __shared__ unsigned short XA[2][6528];
  __shared__ float AWL[4][2][64];
  int b = blockIdx.x & 7, r2b = blockIdx.x >> 3;
  int ht = r2b / 5, wt = r2b % 5;
  int h0 = ht * 4, w0 = wt * 32;
  int tid = threadIdx.x, lane = tid & 63, wv = tid >> 6;
  int l15 = lane & 15, l4 = lane >> 4;
  int mh = wv >> 1, nh = wv & 1;

  f32x4 acc[4][4];
#pragma unroll
  for (int j = 0; j < 4; ++j)
#pragma unroll
    for (int nt = 0; nt < 4; ++nt) acc[j][nt] = (f32x4){0.f, 0.f, 0.f, 0.f};

  // ---------------- PASS A: embed 1x1 conv from global x ----------------
#pragma unroll
  for (int cs = 0; cs < 4; ++cs) {
    short8 A[4], Bf[4];
#pragma unroll
    for (int j = 0; j < 4; ++j) {
      int h = h0 + mh * 2 + (j >> 1);
      int w = w0 + (j & 1) * 16 + l15;
      const float* xp = x + ((size_t)(b * 128 + cs * 32 + l4 * 8)) * 25600 + h * 160 + w;
#pragma unroll
      for (int u = 0; u < 8; ++u) A[j][u] = (short)f2bf(xp[(size_t)u * 25600]);
    }
#pragma unroll
    for (int nt = 0; nt < 4; ++nt)
      Bf[nt] = *(const short8*)(W1t + (nt * 16 + l15) * 128 + cs * 32 + l4 * 8);
#pragma unroll
    for (int j = 0; j < 4; ++j)
#pragma unroll
      for (int nt = 0; nt < 4; ++nt)
        acc[j][nt] = __builtin_amdgcn_mfma_f32_16x16x32_bf16(A[j], Bf[nt],
                                                             acc[j][nt], 0, 0, 0);
  }

  // E write to LDS (nh==0 waves only): [pxl][slot(ce>>3)^(pxl&7)][ce&7]
  unsigned short* E = &XA[0][0];
  if (nh == 0) {
#pragma unroll
    for (int j = 0; j < 4; ++j)
#pragma unroll
      for (int nt = 0; nt < 4; ++nt)
#pragma unroll
        for (int r = 0; r < 4; ++r) {
          int pxl = (mh * 2 + (j >> 1)) * 32 + (j & 1) * 16 + l4 * 4 + r;
          int ce = nt * 16 + l15;
          int slot = (ce >> 3) ^ (pxl & 7);
          E[pxl * 64 + slot * 8 + (ce & 7)] = f2bf(acc[j][nt][r]);
        }
  }
  __syncthreads();

  // ---------------- scores + max + sigmoid -> AWL ----------------
  const f32x4 zf = (f32x4){0.f, 0.f, 0.f, 0.f};
#pragma unroll
  for (int hh = 0; hh < 2; ++hh) {
    int head = nh * 2 + hh;
    short8 Ga[5];
    f32x4 cst[5];
#pragma unroll
    for (int m5 = 0; m5 < 5; ++m5) {
      Ga[m5] = *(const short8*)(Gpad + (((size_t)b * 4 + head) * 80 + m5 * 16 + l15) * 32 + l4 * 8);
      cst[m5] = *(const f32x4*)(Cst + ((size_t)b * 4 + head) * 80 + m5 * 16 + l4 * 4);
    }
    float bias = attn_bias[head];
#pragma unroll
    for (int nt = 0; nt < 4; ++nt) {
      int pxl = mh * 64 + nt * 16 + l15;
      int rslot = (head * 2 + (l4 & 1)) ^ (pxl & 7);  // l4>=2 rereads: garbage-ok (Gpad zeros)
      short8 Bf = *(const short8*)(E + pxl * 64 + rslot * 8);
      float mx = -3.0e38f;
#pragma unroll
      for (int m5 = 0; m5 < 5; ++m5) {
        f32x4 s = __builtin_amdgcn_mfma_f32_16x16x32_bf16(Ga[m5], Bf, zf, 0, 0, 0);
#pragma unroll
        for (int r = 0; r < 4; ++r) mx = fmaxf(mx, s[r] + cst[m5][r]);
      }
      mx = fmaxf(mx, __shfl_xor(mx, 16));
      mx = fmaxf(mx, __shfl_xor(mx, 32));
      if (lane < 16) AWL[wv][hh][nt * 16 + lane] = 1.f / (1.f + __expf(-(mx * 0.25f + bias)));
    }
  }
  __syncthreads();   // E reads done; XA free for conv staging

  // ---------------- PASS B: 3x3 conv, cs-chunked dbuf staging ----------------
#pragma unroll
  for (int j = 0; j < 4; ++j)
#pragma unroll
    for (int nt = 0; nt < 4; ++nt) acc[j][nt] = (f32x4){0.f, 0.f, 0.f, 0.f};

  // staging geometry: thread q<204 owns (row=q/34, p=q%34);
  // h = h0+row-1, w = w0-1+p; zero-fill out-of-image
  int q = tid, row = q / 34, p = q - row * 34;
  bool sv = (q < 204);
  int hs = h0 + row - 1, ws = w0 - 1 + p;
  bool inb = sv && (hs >= 0) && (hs < 160) && (ws >= 0) && (ws < 160);
  const float* xs = x + (size_t)(b * 128) * 25600 + hs * 160 + ws;
  int cb = (row * 34 + p) * 4;
  int psw = (p >> 1) & 3;

  float xf[32];
#pragma unroll
  for (int c = 0; c < 32; ++c) xf[c] = inb ? xs[(size_t)c * 25600] : 0.f;
#pragma unroll
  for (int s = 0; s < 4; ++s) {
    short8 v;
#pragma unroll
    for (int u = 0; u < 8; ++u) v[u] = (short)f2bf(xf[s * 8 + u]);
    if (sv) *(short8*)(&XA[0][(cb + (s ^ psw)) * 8]) = v;
  }
  __syncthreads();

  for (int cs = 0; cs < 4; ++cs) {
    // issue next chunk's global loads early (T14)
    if (cs < 3) {
#pragma unroll
      for (int c = 0; c < 32; ++c)
        xf[c] = inb ? xs[(size_t)((cs + 1) * 32 + c) * 25600] : 0.f;
    }
#pragma unroll
    for (int tap = 0; tap < 9; ++tap) {
      int ky = tap / 3, kx = tap - ky * 3;
      short8 A[4], Bf[4];
#pragma unroll
      for (int j = 0; j < 4; ++j) {
        int rr = mh * 2 + (j >> 1) + ky;
        int p2 = (j & 1) * 16 + l15 + kx;
        A[j] = *(const short8*)(&XA[cs & 1][((rr * 34 + p2) * 4 + (l4 ^ ((p2 >> 1) & 3))) * 8]);
      }
#pragma unroll
      for (int nt = 0; nt < 4; ++nt)
        Bf[nt] = *(const short8*)(Wpt + (size_t)(cs * 9 + tap) * 4096 +
                                  (nh * 64 + nt * 16 + l15) * 32 + l4 * 8);
#pragma unroll
      for (int j = 0; j < 4; ++j)
#pragma unroll
        for (int nt = 0; nt < 4; ++nt)
          acc[j][nt] = __builtin_amdgcn_mfma_f32_16x16x32_bf16(A[j], Bf[nt],
                                                               acc[j][nt], 0, 0, 0);
    }
    // write-late + single barrier per cs
    if (cs < 3) {
#pragma unroll
      for (int s = 0; s < 4; ++s) {
        short8 v;
#pragma unroll
        for (int u = 0; u < 8; ++u) v[u] = (short)f2bf(xf[s * 8 + u]);
        if (sv) *(short8*)(&XA[(cs + 1) & 1][(cb + (s ^ psw)) * 8]) = v;
      }
      __syncthreads();
    }
  }

  // ---------------- epilogue: BN + gate + store ----------------
  float s2v[4], t2v[4];
#pragma unroll
  for (int nt = 0; nt < 4; ++nt) {
    int co = nh * 64 + nt * 16 + l15;
    s2v[nt] = s2[co];
    t2v[nt] = t2[co];
  }
#pragma unroll
  for (int j = 0; j < 4; ++j) {
    int h = h0 + mh * 2 + (j >> 1);
    int wbase = w0 + (j & 1) * 16 + l4 * 4;
    int pb = (j >> 1) * 32 + (j & 1) * 16 + l4 * 4;
    f32x4 a0 = *(const f32x4*)(&AWL[wv][0][pb]);
    f32x4 a1 = *(const f32x4*)(&AWL[wv][1][pb]);
#pragma unroll
    for (int nt = 0; nt < 4; ++nt) {
      int co = nh * 64 + nt * 16 + l15;
      f32x4 g = (nt >> 1) ? a1 : a0;
      f32x4 o;
#pragma unroll
      for (int r = 0; r < 4; ++r) o[r] = (acc[j][nt][r] * s2v[nt] + t2v[nt]) * g[r];
      *(f32x4*)(out + (size_t)(b * 128 + co) * 25600 + h * 160 + wbase) = o;
    }
  }
}

// ------------------------------------------------------------------
extern "C" void kernel_launch(void* const* d_in, const int* in_sizes, int n_in,
                              void* d_out, int out_size, void* d_ws, size_t ws_size,
                              hipStream_t stream) {
  (void)in_sizes; (void)n_in; (void)out_size; (void)ws_size;
  const float* x         = (const float*)d_in[0];
  const float* guide     = (const float*)d_in[1];
  const float* w_embed   = (const float*)d_in[2];
  const float* g1        = (const float*)d_in[3];
  const float* b1        = (const float*)d_in[4];
  const float* rm1       = (const float*)d_in[5];
  const float* rv1       = (const float*)d_in[6];
  const float* Wg        = (const float*)d_in[7];
  const float* bg        = (const float*)d_in[8];
  const float* attn_bias = (const float*)d_in[9];
  const float* w_proj    = (const float*)d_in[10];
  const float* g2        = (const float*)d_in[11];
  const float* b2        = (const float*)d_in[12];
  const float* rm2       = (const float*)d_in[13];
  const float* rv2       = (const float*)d_in[14];
  float* out = (float*)d_out;

  char* ws = (char*)d_ws;
  unsigned short* W1t  = (unsigned short*)(ws);             //  16,384 B
  unsigned short* Wpt  = (unsigned short*)(ws + 16384);     // 294,912 B
  unsigned short* Gpad = (unsigned short*)(ws + 311296);    // 163,840 B
  float* Cst           = (float*)(ws + 475136);             //  10,240 B
  float* s2            = (float*)(ws + 485376);             //     512 B
  float* t2            = (float*)(ws + 485888);             //     512 B
  // total ws usage: 486,400 B

  k_prep_misc<<<609, 256, 0, stream>>>(w_embed, w_proj, g2, b2, rm2, rv2, W1t, Wpt, s2, t2);
  k_guide<<<640, 64, 0, stream>>>(guide, Wg, bg, g1, b1, rm1, rv1, Gpad, Cst);
  k_mega<<<1600, 256, 0, stream>>>(x, W1t, Wpt, Gpad, Cst, attn_bias, s2, t2, out);
}

// Round 6
// 162.327 us; speedup vs baseline: 1.1509x; 1.1509x over previous
//
#include <hip/hip_runtime.h>
#include <hip/hip_bf16.h>
#include <stdint.h>

// ---- constants ----
// B=8, Cin=128, H=W=160, Ce=64, NH=4, HC=16, N=80, Cg=512, Co=128
// P2: bf16, cs-major planes [4 cs][8 b][162][176][32 ci]
//     interior (h,w) -> (h+1, w+8); borders zero.
// k_mega: per [4h x 32w]x[128 co] tile: conv cs-loop (A from LDS dbuf,
//   B reg-prefetched from L2); embed rides tap(1,1)'s A-frags; then
//   scores MFMA vs Gpad -> max -> sigmoid -> gate -> store.

typedef __attribute__((ext_vector_type(8))) short short8;
typedef __attribute__((ext_vector_type(4))) float f32x4;

#define PCH2 ((size_t)8 * 162 * 176 * 32)   // elements per cs-plane

__device__ __forceinline__ unsigned short f2bf(float f) {
  unsigned int u = __float_as_uint(f);
  u += 0x7fff + ((u >> 16) & 1);   // round-to-nearest-even
  return (unsigned short)(u >> 16);
}

__device__ __forceinline__ short8 zero8() {
  short8 z = {0,0,0,0,0,0,0,0};
  return z;
}

// ------------------------------------------------------------------
// P0: x fp32 NCHW -> bf16 cs-major padded planes, zero borders
// ------------------------------------------------------------------
__global__ __launch_bounds__(192) void k_prep_x(const float* __restrict__ x,
                                                unsigned short* __restrict__ P2) {
  int b = blockIdx.x / 162, hp = blockIdx.x % 162;
  int wp = threadIdx.x;
  if (wp >= 176) return;
  size_t pix = (((size_t)b * 162 + hp) * 176 + wp) * 32;
  bool interior = (hp >= 1) && (hp <= 160) && (wp >= 8) && (wp < 168);
  if (!interior) {
#pragma unroll
    for (int cs = 0; cs < 4; ++cs)
#pragma unroll
      for (int s = 0; s < 4; ++s)
        *(short8*)(&P2[(size_t)cs * PCH2 + pix + s * 8]) = zero8();
    return;
  }
  int h = hp - 1, w = wp - 8;
  const float* xb = x + (size_t)b * 128 * 25600 + h * 160 + w;
  for (int cs = 0; cs < 4; ++cs) {
#pragma unroll
    for (int s = 0; s < 4; ++s) {
      short8 v;
#pragma unroll
      for (int j = 0; j < 8; ++j) {
        float f = xb[(size_t)(cs * 32 + s * 8 + j) * 25600];
        v[j] = (short)f2bf(f);
      }
      *(short8*)(&P2[(size_t)cs * PCH2 + pix + s * 8]) = v;
    }
  }
}

// ------------------------------------------------------------------
// P1: weight conversions + BN2 folding
//   W1t [64 ce][128 ci] bf16
//   Wpt [4 cs][9 tap][128 co][32 ci] bf16   (slab t = cs*9+tap at t*4096)
//   s2,t2 [128] f32
// ------------------------------------------------------------------
__global__ __launch_bounds__(256) void k_prep_misc(
    const float* __restrict__ w_embed, const float* __restrict__ w_proj,
    const float* __restrict__ g2, const float* __restrict__ b2,
    const float* __restrict__ rm2, const float* __restrict__ rv2,
    unsigned short* __restrict__ W1t, unsigned short* __restrict__ Wpt,
    float* __restrict__ s2, float* __restrict__ t2) {
  int idx = blockIdx.x * 256 + threadIdx.x;
  if (idx < 8192) { W1t[idx] = f2bf(w_embed[idx]); return; }
  idx -= 8192;
  if (idx < 147456) {
    int cs = idx / 36864, r = idx - cs * 36864;
    int tap = r >> 12, r2 = r & 4095;
    int co = r2 >> 5, ci5 = r2 & 31;
    int ci = cs * 32 + ci5;
    Wpt[idx] = f2bf(w_proj[(co * 128 + ci) * 9 + tap]);
    return;
  }
  idx -= 147456;
  if (idx < 128) {
    float s = g2[idx] * rsqrtf(rv2[idx] + 1e-3f);
    s2[idx] = s;
    t2[idx] = b2[idx] - rm2[idx] * s;
  }
}

// ------------------------------------------------------------------
// P2k: guide GEMM + BN1 folding
//   Gpad [8][4][80][32] bf16  (k<16: g_raw*s1 ; k>=16: 0)
//   Cst  [8][4][80] f32       (dot(g_raw, t1) per head)
// ------------------------------------------------------------------
__global__ __launch_bounds__(64) void k_guide(
    const float* __restrict__ guide, const float* __restrict__ Wg,
    const float* __restrict__ bg, const float* __restrict__ g1,
    const float* __restrict__ b1, const float* __restrict__ rm1,
    const float* __restrict__ rv1, unsigned short* __restrict__ Gpad,
    float* __restrict__ Cst) {
  int b = blockIdx.x / 80, n = blockIdx.x % 80;
  __shared__ float gs[512];
  const float* gr = guide + ((size_t)b * 80 + n) * 512;
  for (int i = threadIdx.x; i < 512; i += 64) gs[i] = gr[i];
  __syncthreads();
  int ce = threadIdx.x;
  const float* wr = Wg + (size_t)ce * 512;
  float acc = 0.f;
  for (int k = 0; k < 512; k += 4)
    acc += gs[k] * wr[k] + gs[k + 1] * wr[k + 1] + gs[k + 2] * wr[k + 2] +
           gs[k + 3] * wr[k + 3];
  float raw = acc + bg[ce];
  float s1 = g1[ce] * rsqrtf(rv1[ce] + 1e-3f);
  float t1 = b1[ce] - rm1[ce] * s1;
  int head = ce >> 4, c = ce & 15;
  size_t gp = (((size_t)b * 4 + head) * 80 + n) * 32;
  Gpad[gp + c] = f2bf(raw * s1);
  Gpad[gp + 16 + c] = 0;
  float cp = raw * t1;
  cp += __shfl_xor(cp, 1);
  cp += __shfl_xor(cp, 2);
  cp += __shfl_xor(cp, 4);
  cp += __shfl_xor(cp, 8);
  if (c == 0) Cst[((size_t)b * 4 + head) * 80 + n] = cp;
}

// ------------------------------------------------------------------
// K: fused conv+attn mega kernel (reads bf16 P2).
// Block tile [4h x 32w] x [128 co]; 4 waves = 2M(px) x 2N(co).
// XCD-chunked: b = blk&7.
// LDS: XA 2 x 15,360 B ([6 rows][40 px][4 slots][16B], slot-XOR swz)
//      overlaid by E [128 px][8 slots][16B] = 16 KB after the loop;
//      + AWL [4 wv][2][64] f32 = 2 KB.  Total 32,768 B.
// B-frags (Wpt): register pipeline, 2 K-steps ahead, direct from L2.
// Embed (1x1): reuses tap(ky=1,kx=1) A-frags; accE -> E -> scores.
// ------------------------------------------------------------------
__global__ __launch_bounds__(256, 2) void k_mega(
    const unsigned short* __restrict__ P2, const unsigned short* __restrict__ W1t,
    const unsigned short* __restrict__ Wpt, const unsigned short* __restrict__ Gpad,
    const float* __restrict__ Cst, const float* __restrict__ attn_bias,
    const float* __restrict__ s2, const float* __restrict__ t2,
    float* __restrict__ out) {
  __shared__ unsigned short XA[2][7680];
  __shared__ float AWL[4][2][64];
  int b = blockIdx.x & 7, r2b = blockIdx.x >> 3;
  int ht = r2b / 5, wt = r2b % 5;
  int h0 = ht * 4, w0 = wt * 32;
  int tid = threadIdx.x, lane = tid & 63, wv = tid >> 6;
  int l15 = lane & 15, l4 = lane >> 4;
  int mh = wv >> 1, nh = wv & 1;

  // A staging decode (R4-proven): LDS chunk c=i*256+tid <- (row,px,slot)
  size_t aoff[4];
  bool aval[4];
#pragma unroll
  for (int i = 0; i < 4; ++i) {
    int c = i * 256 + tid;
    aval[i] = (c < 960);
    int cc = aval[i] ? c : 0;
    int row = cc / 160, rem = cc - row * 160;
    int px = rem >> 2, sp = rem & 3;
    int s = sp ^ ((px >> 1) & 3);
    aoff[i] = (((size_t)b * 162 + h0 + row) * 176 + (w0 + 7 + px)) * 32 + s * 8;
  }
  // A-frag read chunk bases (row term added per tap)
  int abase[2][3];
#pragma unroll
  for (int wh = 0; wh < 2; ++wh)
#pragma unroll
    for (int kx = 0; kx < 3; ++kx) {
      int px = wh * 16 + l15 + kx;
      abase[wh][kx] = px * 4 + (l4 ^ ((px >> 1) & 3));
    }
  // B-frag global offset (per t slab of 4096)
  int bfo = (nh * 64 + l15 * 1 * 16 % 16, 0);  // (dummy to keep formatting sane)
  int bco = (nh * 64 + l15) * 0;               // unused
  int boff[4];
#pragma unroll
  for (int nt = 0; nt < 4; ++nt) boff[nt] = (nh * 64 + nt * 16 + l15) * 32 + l4 * 8;

  f32x4 acc[4][4], accE[4][2];
#pragma unroll
  for (int j = 0; j < 4; ++j) {
#pragma unroll
    for (int nt = 0; nt < 4; ++nt) acc[j][nt] = (f32x4){0.f, 0.f, 0.f, 0.f};
#pragma unroll
    for (int ne = 0; ne < 2; ++ne) accE[j][ne] = (f32x4){0.f, 0.f, 0.f, 0.f};
  }

  short8 areg[4];
  // prologue: stage A(cs=0)
#pragma unroll
  for (int i = 0; i < 4; ++i)
    if (aval[i]) areg[i] = *(const short8*)(P2 + aoff[i]);
#pragma unroll
  for (int i = 0; i < 4; ++i)
    if (aval[i]) *(short8*)(&XA[0][(i * 256 + tid) * 8]) = areg[i];

  // B register pipeline: 3-slot rotation, 2 steps ahead
  short8 Bbuf[3][4];
#pragma unroll
  for (int nt = 0; nt < 4; ++nt) {
    Bbuf[0][nt] = *(const short8*)(Wpt + boff[nt]);
    Bbuf[1][nt] = *(const short8*)(Wpt + 4096 + boff[nt]);
  }
  __syncthreads();

#pragma unroll
  for (int cs = 0; cs < 4; ++cs) {
    // issue next A chunk's global loads early (T14)
    if (cs < 3) {
#pragma unroll
      for (int i = 0; i < 4; ++i)
        if (aval[i]) areg[i] = *(const short8*)(P2 + (size_t)(cs + 1) * PCH2 + aoff[i]);
    }
#pragma unroll
    for (int tap = 0; tap < 9; ++tap) {
      const int t = cs * 9 + tap;
      // prefetch B for t+2
      if (t + 2 < 36) {
#pragma unroll
        for (int nt = 0; nt < 4; ++nt)
          Bbuf[(t + 2) % 3][nt] =
              *(const short8*)(Wpt + (size_t)(t + 2) * 4096 + boff[nt]);
      }
      int ky = tap / 3, kx = tap - ky * 3;
      short8 A[4];
#pragma unroll
      for (int j = 0; j < 4; ++j) {
        int rr = mh * 2 + (j >> 1) + ky;
        A[j] = *(const short8*)(&XA[cs & 1][(rr * 160 + abase[j & 1][kx]) * 8]);
      }
      if (tap == 4) {  // embed rides the center tap's A-frags
        short8 BE[2];
#pragma unroll
        for (int ne = 0; ne < 2; ++ne)
          BE[ne] = *(const short8*)(W1t + (nh * 32 + ne * 16 + l15) * 128 +
                                    cs * 32 + l4 * 8);
#pragma unroll
        for (int j = 0; j < 4; ++j)
#pragma unroll
          for (int ne = 0; ne < 2; ++ne)
            accE[j][ne] = __builtin_amdgcn_mfma_f32_16x16x32_bf16(
                A[j], BE[ne], accE[j][ne], 0, 0, 0);
      }
#pragma unroll
      for (int j = 0; j < 4; ++j)
#pragma unroll
        for (int nt = 0; nt < 4; ++nt)
          acc[j][nt] = __builtin_amdgcn_mfma_f32_16x16x32_bf16(
              A[j], Bbuf[t % 3][nt], acc[j][nt], 0, 0, 0);
    }
    // write-late + single barrier per cs
    if (cs < 3) {
#pragma unroll
      for (int i = 0; i < 4; ++i)
        if (aval[i]) *(short8*)(&XA[(cs + 1) & 1][(i * 256 + tid) * 8]) = areg[i];
      __syncthreads();
    }
  }
  __syncthreads();  // all XA reads done; overlay E

  // E write: [pxl][slot(ce>>3)^(pxl&7)][ce&7], pxl = mh*64 + ...
  unsigned short* E = &XA[0][0];
#pragma unroll
  for (int j = 0; j < 4; ++j)
#pragma unroll
    for (int ne = 0; ne < 2; ++ne)
#pragma unroll
      for (int r = 0; r < 4; ++r) {
        int pxl = mh * 64 + (j >> 1) * 32 + (j & 1) * 16 + l4 * 4 + r;
        int ce = nh * 32 + ne * 16 + l15;
        int slot = (ce >> 3) ^ (pxl & 7);
        E[pxl * 64 + slot * 8 + (ce & 7)] = f2bf(accE[j][ne][r]);
      }
  __syncthreads();

  // scores + max + sigmoid -> AWL (wave-private)
  const f32x4 zf = (f32x4){0.f, 0.f, 0.f, 0.f};
#pragma unroll
  for (int hh = 0; hh < 2; ++hh) {
    int head = nh * 2 + hh;
    short8 Ga[5];
    f32x4 cst[5];
#pragma unroll
    for (int m5 = 0; m5 < 5; ++m5) {
      Ga[m5] = *(const short8*)(Gpad + (((size_t)b * 4 + head) * 80 + m5 * 16 + l15) * 32 + l4 * 8);
      cst[m5] = *(const f32x4*)(Cst + ((size_t)b * 4 + head) * 80 + m5 * 16 + l4 * 4);
    }
    float bias = attn_bias[head];
#pragma unroll
    for (int nt = 0; nt < 4; ++nt) {
      int pxl = mh * 64 + nt * 16 + l15;
      int rslot = (head * 2 + (l4 & 1)) ^ (pxl & 7);  // l4>=2 rereads: garbage-ok (Gpad zeros)
      short8 Bf = *(const short8*)(E + pxl * 64 + rslot * 8);
      float mx = -3.0e38f;
#pragma unroll
      for (int m5 = 0; m5 < 5; ++m5) {
        f32x4 s = __builtin_amdgcn_mfma_f32_16x16x32_bf16(Ga[m5], Bf, zf, 0, 0, 0);
#pragma unroll
        for (int r = 0; r < 4; ++r) mx = fmaxf(mx, s[r] + cst[m5][r]);
      }
      mx = fmaxf(mx, __shfl_xor(mx, 16));
      mx = fmaxf(mx, __shfl_xor(mx, 32));
      if (lane < 16) AWL[wv][hh][nt * 16 + lane] = 1.f / (1.f + __expf(-(mx * 0.25f + bias)));
    }
  }

  // epilogue: BN + gate + store (AWL is wave-private; no barrier needed)
  float s2v[4], t2v[4];
#pragma unroll
  for (int nt = 0; nt < 4; ++nt) {
    int co = nh * 64 + nt * 16 + l15;
    s2v[nt] = s2[co];
    t2v[nt] = t2[co];
  }
#pragma unroll
  for (int j = 0; j < 4; ++j) {
    int h = h0 + mh * 2 + (j >> 1);
    int wbase = w0 + (j & 1) * 16 + l4 * 4;
    int pb = (j >> 1) * 32 + (j & 1) * 16 + l4 * 4;
    f32x4 a0 = *(const f32x4*)(&AWL[wv][0][pb]);
    f32x4 a1 = *(const f32x4*)(&AWL[wv][1][pb]);
#pragma unroll
    for (int nt = 0; nt < 4; ++nt) {
      int co = nh * 64 + nt * 16 + l15;
      f32x4 g = (nt >> 1) ? a1 : a0;
      f32x4 o;
#pragma unroll
      for (int r = 0; r < 4; ++r) o[r] = (acc[j][nt][r] * s2v[nt] + t2v[nt]) * g[r];
      *(f32x4*)(out + (size_t)(b * 128 + co) * 25600 + h * 160 + wbase) = o;
    }
  }
}

// ------------------------------------------------------------------
extern "C" void kernel_launch(void* const* d_in, const int* in_sizes, int n_in,
                              void* d_out, int out_size, void* d_ws, size_t ws_size,
                              hipStream_t stream) {
  (void)in_sizes; (void)n_in; (void)out_size; (void)ws_size;
  const float* x         = (const float*)d_in[0];
  const float* guide     = (const float*)d_in[1];
  const float* w_embed   = (const float*)d_in[2];
  const float* g1        = (const float*)d_in[3];
  const float* b1        = (const float*)d_in[4];
  const float* rm1       = (const float*)d_in[5];
  const float* rv1       = (const float*)d_in[6];
  const float* Wg        = (const float*)d_in[7];
  const float* bg        = (const float*)d_in[8];
  const float* attn_bias = (const float*)d_in[9];
  const float* w_proj    = (const float*)d_in[10];
  const float* g2        = (const float*)d_in[11];
  const float* b2        = (const float*)d_in[12];
  const float* rm2       = (const float*)d_in[13];
  const float* rv2       = (const float*)d_in[14];
  float* out = (float*)d_out;

  char* ws = (char*)d_ws;
  unsigned short* P2   = (unsigned short*)(ws);               // 58,392,576 B
  unsigned short* W1t  = (unsigned short*)(ws + 58392576);    //     16,384 B
  unsigned short* Wpt  = (unsigned short*)(ws + 58408960);    //    294,912 B
  unsigned short* Gpad = (unsigned short*)(ws + 58703872);    //    163,840 B
  float* Cst           = (float*)(ws + 58867712);             //     10,240 B
  float* s2            = (float*)(ws + 58877952);             //        512 B
  float* t2            = (float*)(ws + 58878464);             //        512 B
  // total ws usage: 58,878,976 B

  k_prep_x<<<8 * 162, 192, 0, stream>>>(x, P2);
  k_prep_misc<<<609, 256, 0, stream>>>(w_embed, w_proj, g2, b2, rm2, rv2, W1t, Wpt, s2, t2);
  k_guide<<<640, 64, 0, stream>>>(guide, Wg, bg, g1, b1, rm1, rv1, Gpad, Cst);
  k_mega<<<1600, 256, 0, stream>>>(P2, W1t, Wpt, Gpad, Cst, attn_bias, s2, t2, out);
}